// Round 7
// baseline (53.477 us; speedup 1.0000x reference)
//
#include <hip/hip_runtime.h>

// BinaryTreeShConv on MI355X (gfx950).
// out[b,v,i] = relu(bias[i] + sum_{p,c,rn} W[i,c,rn] * K[b,v,p,rn] * sig[b, idx[b,v,p], c])
// B=8 V=4096 P=32 C=32 RN=32 OUT=32, CRN=1024.
//
// R6: remove ALL dependent-load chains from the streaming kernel.
//  - prep gathers patches[b,v,p,c] = bf16(sig[b, idx[b,v,p], c]) into d_ws
//    (16.8 MB; sig is L2-resident so the gather is cheap there) + packs Wf.
//  - fused kernel is a pure linear streamer: patches + ck hi-ushort + Wf.
//    No idx, no gathers. Simple per-q loops (R1 style beat explicit pipeline).
//  - __launch_bounds__(256,4): reg headroom without occupancy loss (LDS-capped).

typedef __attribute__((ext_vector_type(8))) short bf16x8;
typedef __attribute__((ext_vector_type(16))) float f32x16;
typedef __attribute__((ext_vector_type(4))) float f32x4;

__device__ __forceinline__ unsigned short f2bf_rne(float f) {
    union { float f; unsigned int u; } x;
    x.f = f;
    unsigned int u = x.u;
    return (unsigned short)((u + 0x7fffu + ((u >> 16) & 1u)) >> 16);
}
__device__ __forceinline__ unsigned short f2bf_rh(float f) {  // round-half-up
    union { float f; unsigned int u; } x;
    x.f = f;
    return (unsigned short)((x.u + 0x8000u) >> 16);
}

// Blocks [0, 16384): patches gather.  Blocks [16384, 16512): Wf pack.
__global__ __launch_bounds__(256) void prep_kernel(
        const float* __restrict__ W, const float* __restrict__ sig,
        const int* __restrict__ pidx,
        unsigned short* __restrict__ Wf, unsigned short* __restrict__ pat) {
    if (blockIdx.x < 16384) {
        // patches: thread -> (bvp = t>>2, octet = t&3); 8 channels each.
        const int t = blockIdx.x * 256 + threadIdx.x;
        const int bvp = t >> 2;               // 0 .. 1,048,575  (b*131072+v*32+p)
        const int c0 = (t & 3) * 8;
        const int row = pidx[bvp];            // broadcast across 4 lanes
        const int b = bvp >> 17;
        const float* src = sig + ((size_t)(b << 12) + row) * 32 + c0;
        f32x4 a = *(const f32x4*)src;
        f32x4 d = *(const f32x4*)(src + 4);
        bf16x8 v;
        v[0] = (short)f2bf_rne(a[0]); v[1] = (short)f2bf_rne(a[1]);
        v[2] = (short)f2bf_rne(a[2]); v[3] = (short)f2bf_rne(a[3]);
        v[4] = (short)f2bf_rne(d[0]); v[5] = (short)f2bf_rne(d[1]);
        v[6] = (short)f2bf_rne(d[2]); v[7] = (short)f2bf_rne(d[3]);
        *(bf16x8*)(pat + (size_t)bvp * 32 + c0) = v;
    } else {
        // Wf[pair=2s+t][lane][j] = bf16(W[i=16t+(lane&15)][crn=32s+8*(lane>>4)+j])
        const int tid = (blockIdx.x - 16384) * 256 + threadIdx.x;   // 0..32767
        int j = tid & 7;
        int l = (tid >> 3) & 63;
        int pair = tid >> 9;                    // s*2 + t
        int s = pair >> 1;
        int t2 = pair & 1;
        int i = 16 * t2 + (l & 15);
        int crn = 32 * s + 8 * (l >> 4) + j;
        Wf[tid] = f2bf_rne(W[i * 1024 + crn]);
    }
}

__global__ __launch_bounds__(256, 4) void fused_kernel(
        const unsigned short* __restrict__ pat, const float* __restrict__ ck,
        const unsigned short* __restrict__ Wf, const float* __restrict__ bias,
        float* __restrict__ out) {
    __shared__ __align__(16) unsigned short T_lds[16 * 1032];  // 33,024 B
    const int tid = threadIdx.x;
    const int l = tid & 63;
    const int w = tid >> 6;          // wave 0..3
    const int m0 = blockIdx.x * 16;  // first bv of this block
    const int cc = l & 31;           // stage-A: A-row (c) and B-col (rn)
    const int g = l >> 5;
    const unsigned short* ckh = (const unsigned short*)ck;   // [2e+1] = bf16-trunc

    // ---- Stage A: wave w computes T for bv_local = 4w .. 4w+3 ----
    // All loads are linear streams now (patches + ck) — no indirection.
    for (int q = 0; q < 4; ++q) {
        const int bvl = w * 4 + q;
        const int m = m0 + bvl;
        const unsigned short* pb = pat + (size_t)m * 1024;   // [32p][32c] bf16
        const size_t kh = ((size_t)m * 1024) * 2 + 1;        // hi-ushort index
        f32x16 acc = {};
        #pragma unroll
        for (int h = 0; h < 2; ++h) {
            bf16x8 af, bfr;
            #pragma unroll
            for (int j = 0; j < 8; ++j) {
                const int p = h * 16 + 8 * g + j;            // k index (same A/B)
                af[j]  = (short)pb[p * 32 + cc];                    // S^T[c][p]
                bfr[j] = (short)ckh[kh + (size_t)(p * 32 + cc) * 2]; // K[p][rn]
            }
            acc = __builtin_amdgcn_mfma_f32_32x32x16_bf16(af, bfr, acc, 0, 0, 0);
        }
        // D map (verified): col=cc, row=(r&3)+8*(r>>2)+4*g ; T[c][rn] bf16
        unsigned short* trow = T_lds + bvl * 1032 + cc + g * 128;
        #pragma unroll
        for (int r = 0; r < 16; ++r)
            trow[((r & 3) + 8 * (r >> 2)) * 32] = f2bf_rh(acc[r]);
    }

    // ---- Stage B Wf prefetch (independent of T; overlaps stage-A tail) ----
    bf16x8 wfa[8], wfb[8];
    #pragma unroll
    for (int si = 0; si < 8; ++si) {
        const int s = 8 * w + si;
        const bf16x8* wrow = (const bf16x8*)(Wf + (size_t)(s * 2) * 512);
        wfa[si] = wrow[l];        // pair 2s+0, coalesced 16B/lane
        wfb[si] = wrow[64 + l];   // pair 2s+1
    }
    __syncthreads();

    // ---- Stage B: wave w handles k-steps s = 8w..8w+7, both i-tiles ----
    f32x4 acc0 = {}, acc1 = {};
    const int lg = l >> 4;
    const int ln = l & 15;
    #pragma unroll
    for (int si = 0; si < 8; ++si) {
        const int s = 8 * w + si;
        const bf16x8 af = *(const bf16x8*)(T_lds + ln * 1032 + s * 32 + 8 * lg);
        acc0 = __builtin_amdgcn_mfma_f32_16x16x32_bf16(af, wfa[si], acc0, 0, 0, 0);
        acc1 = __builtin_amdgcn_mfma_f32_16x16x32_bf16(af, wfb[si], acc1, 0, 0, 0);
    }
    __syncthreads();                      // all T reads done; reuse LDS as f32 buf

    float* red = (float*)T_lds;           // 4 waves * 2 tiles * 256 f32 = 8 KB
    {
        f32x4* rp = (f32x4*)(red + w * 512);
        rp[l]      = acc0;                // [w][t=0][l][r]
        rp[64 + l] = acc1;                // [w][t=1][l][r]
    }
    __syncthreads();

    // 512 outputs: o = t*256 + l*4 + r ; D map: row(bv)=(l>>4)*4+r, col(i)=16t+(l&15)
    #pragma unroll
    for (int o0 = 0; o0 < 2; ++o0) {
        const int o = o0 * 256 + tid;
        float sum = red[o] + red[512 + o] + red[1024 + o] + red[1536 + o];
        const int t  = o >> 8;
        const int ll = (o >> 2) & 63;
        const int r  = o & 3;
        const int bv = ((ll >> 4) << 2) + r;
        const int i  = 16 * t + (ll & 15);
        sum += bias[i];
        out[(size_t)(m0 + bv) * 32 + i] = sum > 0.f ? sum : 0.f;
    }
}

extern "C" void kernel_launch(void* const* d_in, const int* in_sizes, int n_in,
                              void* d_out, int out_size, void* d_ws, size_t ws_size,
                              hipStream_t stream) {
    const float* sig  = (const float*)d_in[0];
    const int*   pidx = (const int*)d_in[1];
    const float* ck   = (const float*)d_in[2];
    const float* W    = (const float*)d_in[3];
    const float* bias = (const float*)d_in[4];
    float* out = (float*)d_out;
    unsigned short* Wf  = (unsigned short*)d_ws;   // 64 KB fragment-ordered W
    unsigned short* pat = Wf + 32768;              // 16.8 MB bf16 patches

    prep_kernel<<<16512, 256, 0, stream>>>(W, sig, pidx, Wf, pat);
    fused_kernel<<<2048, 256, 0, stream>>>(pat, ck, Wf, bias, out);
}

// Round 8
// 49.114 us; speedup vs baseline: 1.0888x; 1.0888x over previous
//
#include <hip/hip_runtime.h>

// BinaryTreeShConv on MI355X (gfx950).
// out[b,v,i] = relu(bias[i] + sum_{p,c,rn} W[i,c,rn] * K[b,v,p,rn] * sig[b, idx[b,v,p], c])
// B=8 V=4096 P=32 C=32 RN=32 OUT=32, CRN=1024.
//
// R7: single-wave blocks (64 thr), 4 bv per block, grid 8192.
//  - LDS 33KB -> 8.3KB: ~19 resident waves/CU (was ~12-16), independent waves,
//    no inter-wave barriers, no k-split reduce (wave does all 32 k-steps).
//  - stage B A-frag row = l&3 (bv replicated to rows 4-15; those D rows are
//    discarded duplicates). Lanes 0-15 store rows 0-3 coalesced.
//  - stage A / prep identical to R1 (best structure, passed 3x, absmax 0.25).

typedef __attribute__((ext_vector_type(8))) short bf16x8;
typedef __attribute__((ext_vector_type(16))) float f32x16;
typedef __attribute__((ext_vector_type(4))) float f32x4;

__device__ __forceinline__ unsigned short f2bf_rne(float f) {
    union { float f; unsigned int u; } x;
    x.f = f;
    unsigned int u = x.u;
    return (unsigned short)((u + 0x7fffu + ((u >> 16) & 1u)) >> 16);
}
__device__ __forceinline__ unsigned short f2bf_rh(float f) {  // round-half-up
    union { float f; unsigned int u; } x;
    x.f = f;
    return (unsigned short)((x.u + 0x8000u) >> 16);
}

// Wf[pair=2s+t][lane][j] = bf16(W[i=16t+(lane&15)][crn=32s+8*(lane>>4)+j])
// plus sig f32 -> bf16 (RNE), 8 elements/thread.
__global__ __launch_bounds__(256) void prep_kernel(
        const float* __restrict__ W, const float* __restrict__ sig,
        unsigned short* __restrict__ Wf, unsigned short* __restrict__ sigbf) {
    int tid = blockIdx.x * 256 + threadIdx.x;
    if (tid < 32768) {
        int j = tid & 7;
        int l = (tid >> 3) & 63;
        int pair = tid >> 9;                    // s*2 + t
        int s = pair >> 1;
        int t = pair & 1;
        int i = 16 * t + (l & 15);
        int crn = 32 * s + 8 * (l >> 4) + j;
        Wf[tid] = f2bf_rne(W[i * 1024 + crn]);
    } else {
        int e = (tid - 32768) * 8;              // sig has 1,048,576 elements
        if (e < 8 * 4096 * 32) {
            f32x4 a = *(const f32x4*)(sig + e);
            f32x4 b = *(const f32x4*)(sig + e + 4);
            bf16x8 v;
            v[0] = (short)f2bf_rne(a[0]); v[1] = (short)f2bf_rne(a[1]);
            v[2] = (short)f2bf_rne(a[2]); v[3] = (short)f2bf_rne(a[3]);
            v[4] = (short)f2bf_rne(b[0]); v[5] = (short)f2bf_rne(b[1]);
            v[6] = (short)f2bf_rne(b[2]); v[7] = (short)f2bf_rne(b[3]);
            *(bf16x8*)(sigbf + e) = v;
        }
    }
}

__global__ __launch_bounds__(64, 4) void fused_kernel(
        const unsigned short* __restrict__ sigbf, const int* __restrict__ pidx,
        const float* __restrict__ ck, const unsigned short* __restrict__ Wf,
        const float* __restrict__ bias, float* __restrict__ out) {
    __shared__ __align__(16) unsigned short T_lds[4 * 1032];   // 8,256 B
    const int l = threadIdx.x;       // single wave per block
    const int m0 = blockIdx.x * 4;   // 4 bv per block (same b)
    const int b = m0 >> 12;
    const int cc = l & 31;           // stage-A: A-row (c) and B-col (rn)
    const int g = l >> 5;
    const unsigned short* sgb = sigbf + (size_t)b * (4096 * 32);
    const unsigned short* ckh = (const unsigned short*)ck;   // [2e+1] = bf16-trunc

    // ---- Stage A: this wave computes T for bv = m0 .. m0+3 ----
    for (int q = 0; q < 4; ++q) {
        const int m = m0 + q;
        const int* idxp = pidx + (size_t)m * 32;
        const size_t kh = ((size_t)m * 1024) * 2 + 1;   // hi-ushort index
        f32x16 acc = {};
        #pragma unroll
        for (int h = 0; h < 2; ++h) {
            bf16x8 af, bfr;
            #pragma unroll
            for (int j = 0; j < 8; ++j) {
                const int p = h * 16 + 8 * g + j;       // k index (same A/B order)
                af[j]  = (short)sgb[idxp[p] * 32 + cc];              // S^T[c][p]
                bfr[j] = (short)ckh[kh + (size_t)(p * 32 + cc) * 2]; // K[p][rn]
            }
            acc = __builtin_amdgcn_mfma_f32_32x32x16_bf16(af, bfr, acc, 0, 0, 0);
        }
        // D map (verified): col=cc, row=(r&3)+8*(r>>2)+4*g ; T[c][rn] bf16
        unsigned short* trow = T_lds + q * 1032 + cc + g * 128;
        #pragma unroll
        for (int r = 0; r < 16; ++r)
            trow[((r & 3) + 8 * (r >> 2)) * 32] = f2bf_rh(acc[r]);
    }
    __syncthreads();   // single-wave: just drains lgkmcnt, near-free

    // ---- Stage B: full k (s = 0..31), A-frag row = l&3 (bv replicated) ----
    // A-frag 16x16x32: lane l supplies A[row=l&15][k=32s+8*(l>>4)+j].
    // For lanes with (l&15)<4, (l&3)==(l&15) -> rows 0-3 correct; rows 4-15
    // are duplicates of 0-3 and their D rows are simply not stored.
    f32x4 acc0 = {}, acc1 = {};
    const int rowl = (l & 3) * 1032 + 8 * (l >> 4);
    #pragma unroll
    for (int s = 0; s < 32; ++s) {
        const bf16x8 af = *(const bf16x8*)(T_lds + rowl + s * 32);
        const bf16x8* wrow = (const bf16x8*)(Wf + (size_t)(s * 2) * 512);
        acc0 = __builtin_amdgcn_mfma_f32_16x16x32_bf16(af, wrow[l],      acc0, 0, 0, 0);
        acc1 = __builtin_amdgcn_mfma_f32_16x16x32_bf16(af, wrow[64 + l], acc1, 0, 0, 0);
    }

    // ---- Epilogue: D rows 0-3 live in lanes 0-15 (row=r, col=l&15) ----
    if (l < 16) {
        const float b0 = bias[l];
        const float b1 = bias[16 + l];
        #pragma unroll
        for (int r = 0; r < 4; ++r) {
            float s0 = acc0[r] + b0;
            float s1 = acc1[r] + b1;
            float* orow = out + (size_t)(m0 + r) * 32;
            orow[l]      = s0 > 0.f ? s0 : 0.f;
            orow[16 + l] = s1 > 0.f ? s1 : 0.f;
        }
    }
}

extern "C" void kernel_launch(void* const* d_in, const int* in_sizes, int n_in,
                              void* d_out, int out_size, void* d_ws, size_t ws_size,
                              hipStream_t stream) {
    const float* sig  = (const float*)d_in[0];
    const int*   pidx = (const int*)d_in[1];
    const float* ck   = (const float*)d_in[2];
    const float* W    = (const float*)d_in[3];
    const float* bias = (const float*)d_in[4];
    float* out = (float*)d_out;
    unsigned short* Wf    = (unsigned short*)d_ws;       // 64 KB fragment-ordered W
    unsigned short* sigbf = Wf + 32768;                  // 2 MB bf16 signal

    prep_kernel<<<640, 256, 0, stream>>>(W, sig, Wf, sigbf);
    fused_kernel<<<8192, 64, 0, stream>>>(sigbf, pidx, ck, Wf, bias, out);
}